// Round 19
// baseline (106.534 us; speedup 1.0000x reference)
//
#include <hip/hip_runtime.h>
#include <hip/hip_bf16.h>

typedef __attribute__((ext_vector_type(4))) float  f32x4;
typedef __attribute__((ext_vector_type(8))) _Float16 f16x8;

static __device__ __forceinline__ void gld_lds16(const void* g, void* l) {
    __builtin_amdgcn_global_load_lds(
        (const __attribute__((address_space(1))) void*)g,
        (__attribute__((address_space(3))) void*)l, 16, 0, 0);
}

// ---- weight pre-transform: w1 -> Bt1[64 n][32 k] f16; w2 -> Bt2[9 tap][128 c2][64 c1] f16
__global__ void transform_kernel(const float* __restrict__ w1, const float* __restrict__ w2,
                                 _Float16* __restrict__ Bt1, _Float16* __restrict__ Bt2)
{
    const int i = blockIdx.x * 256 + threadIdx.x;
    if (i < 64 * 32) {
        const int n = i >> 5, k = i & 31;
        const float v = (k < 27) ? w1[n * 27 + k] : 0.0f;
        Bt1[i] = (_Float16)v;
    }
    const int j = i - 64 * 32;
    if (j >= 0 && j < 9 * 128 * 64) {
        const int tap = j / (128 * 64);
        const int rem = j % (128 * 64);
        const int n = rem >> 6;          // c2
        const int c1 = rem & 63;
        Bt2[j] = (_Float16)w2[((size_t)n * 64 + c1) * 9 + tap];
    }
}

// ---- conv1 (r17-measured-best): patch-LDS gather, direct fragment build (no im2col),
// out_t swizzle staging + coalesced dump. h1: parity-split pixel + c1 XOR-swizzle.
__global__ __launch_bounds__(256) void conv1_mfma(
    const float* __restrict__ x, const float* __restrict__ l,
    const _Float16* __restrict__ Bt1, const float* __restrict__ b1,
    _Float16* __restrict__ h1, int bk0)
{
    const int img = blockIdx.y;
    const int bk  = bk0 + img;
    const int b   = bk / 3, ksc = bk % 3;
    const int step = 1 << ksc;
    const int half = 32 << ksc;
    const int py0 = blockIdx.x * 4;          // first patch row of this block

    const float ly = l[b * 2 + 0], lx = l[b * 2 + 1];
    int cy = (int)floorf(0.5f * (ly + 1.0f) * 512.0f);
    int cx = (int)floorf(0.5f * (lx + 1.0f) * 512.0f);
    cy = min(max(cy, 0), 512);
    cx = min(max(cx, 0), 512);
    const int sy = cy - half, sx = cx - half;

    __shared__ float    patch[3 * 6 * 66];   // 4.75 KB unique gather window
    __shared__ _Float16 out_t[256 * 64];     // 32 KB swizzled output tile

    const int t = threadIdx.x;
    const float* xb = x + (size_t)b * 3 * 512 * 512;
    for (int i = t; i < 3 * 6 * 66; i += 256) {
        const int c  = i / 396, r = i % 396;
        const int ry = r / 66, xx = r % 66;
        const int yy = py0 - 1 + ry;
        const int col = xx - 1;
        const int iy = sy + yy * step, ix = sx + col * step;
        float v = 0.0f;
        if (yy >= 0 && yy < 64 && col >= 0 && col < 64 &&
            iy >= 0 && iy < 512 && ix >= 0 && ix < 512)
            v = xb[(size_t)c * 262144 + iy * 512 + ix];
        patch[i] = v;
    }
    __syncthreads();

    const int wave = t >> 6, lane = t & 63;
    const int lrow = lane & 15, kb = lane >> 4;

    int offj[8];
    #pragma unroll
    for (int j = 0; j < 8; ++j) {
        const int k  = kb * 8 + j;
        const int c  = (k * 57) >> 9;        // k/9 (k < 512)
        const int rr = k - c * 9;
        const int kh = (rr * 43) >> 7;       // rr/3 (rr < 9)
        const int kw = rr - kh * 3;
        offj[j] = (k < 27) ? (c * 396 + kh * 66 + kw) : -1;
    }

    f16x8 bfr[4];
    #pragma unroll
    for (int nf = 0; nf < 4; ++nf)
        bfr[nf] = *(const f16x8*)(Bt1 + ((size_t)(nf * 16 + lrow)) * 32 + kb * 8);

    f32x4 acc[4][4];
    #pragma unroll
    for (int mf = 0; mf < 4; ++mf)
        #pragma unroll
        for (int nf = 0; nf < 4; ++nf)
            #pragma unroll
            for (int r = 0; r < 4; ++r) acc[mf][nf][r] = 0.0f;

    #pragma unroll
    for (int mf = 0; mf < 4; ++mf) {
        const int pix   = (wave * 4 + mf) * 16 + lrow;
        const int pbase = (pix >> 6) * 66 + (pix & 63);
        f16x8 afr;
        #pragma unroll
        for (int j = 0; j < 8; ++j)
            afr[j] = (offj[j] >= 0) ? (_Float16)patch[offj[j] + pbase] : (_Float16)0.0f;
        #pragma unroll
        for (int nf = 0; nf < 4; ++nf)
            acc[mf][nf] = __builtin_amdgcn_mfma_f32_16x16x32_f16(afr, bfr[nf], acc[mf][nf], 0, 0, 0);
    }

    #pragma unroll
    for (int mf = 0; mf < 4; ++mf) {
        const int ml0 = (wave * 4 + mf) * 16 + kb * 4;
        #pragma unroll
        for (int nf = 0; nf < 4; ++nf) {
            const int c1 = nf * 16 + lrow;
            const float bb = b1[c1];
            #pragma unroll
            for (int r = 0; r < 4; ++r) {
                const float v = fmaxf(acc[mf][nf][r] + bb, 0.0f);
                const int ml = ml0 + r;
                const int xcol = ml & 63;
                const int psx = ((xcol & 1) << 5) | (xcol >> 1);   // parity split
                const int pl  = (ml & ~63) | psx;
                const int c1s = c1 ^ ((psx & 7) << 3);             // bank swizzle
                out_t[pl * 64 + c1s] = (_Float16)v;
            }
        }
    }
    __syncthreads();

    _Float16* hb = h1 + (size_t)img * 4096 * 64 + (size_t)py0 * 64 * 64;
    #pragma unroll
    for (int j = 0; j < 8; ++j) {
        const int idx = j * 256 + t;
        *(f16x8*)(hb + (size_t)idx * 8) = *(const f16x8*)&out_t[idx * 8];
    }
}

// ---- conv2: 18-phase ring-4 counted-vmcnt pipeline (T3+T4). Same geometry/bytes as r8:
// block (img, mc: 2 out rows) x N=128, waves 2x2, wave tile M=32 x N=64.
// A slab 5 rows 40KB staged once; B ring 4 x 8KB units (tap,c1h), prefetch depth 3.
// Phase: vmcnt(4) -> s_barrier -> sched_barrier -> stage(u+3) -> compute(u).
__global__ __launch_bounds__(256) void conv2_mfma(
    const _Float16* __restrict__ h1, const _Float16* __restrict__ Bt2,
    const float* __restrict__ b2, float* __restrict__ out, int bk0)
{
    const int img = blockIdx.y;
    const int bk  = bk0 + img;
    const int mc  = blockIdx.x;               // 0..15 : 2 out rows (64 px)
    const int t = threadIdx.x, wave = t >> 6, lane = t & 63;
    const int lrow = lane & 15, kb = lane >> 4;
    const int wq = wave >> 1;                 // M half (0..1)
    const int wn = wave & 1;                  // N half (0..1)

    __shared__ _Float16 As[5 * 4096 + 4 * 4096];   // 40KB A + 4x8KB B ring = 72KB
    _Float16* Bs = As + 5 * 4096;

    const _Float16* hb = h1 + (size_t)img * 4096 * 64;
    const int ys = mc * 4;
    const int nrows = (mc == 15) ? 4 : 5;

    if (mc == 15) {                            // zero pad_high row (y=64)
        f16x8 z = {};
        *(f16x8*)&As[4 * 4096 + t * 16]     = z;
        *(f16x8*)&As[4 * 4096 + t * 16 + 8] = z;
    }

    {   // stage A slab (linear dest; source carries h1 layout directly)
        const _Float16* ga = hb + (size_t)ys * 4096;
        #pragma unroll
        for (int j = 0; j < 10; ++j) {
            if (j < nrows * 2) {
                const int c = j * 256 + t;
                gld_lds16(ga + (size_t)c * 8, As + (j * 256 + wave * 64) * 8);
            }
        }
    }

    // stage B unit u = (tap = u>>1, c1h = u&1): 8KB = [c2 r][4 chunks of 8], swizzle
    // content[r][jh] = src chunk (jh ^ ((r>>1)&3)); read(kb) at [r][kb ^ ((r>>1)&3)].
#define BSTAGE(u)                                                                 \
    {                                                                             \
        const int tap_ = (u) >> 1, c1h_ = (u) & 1, slot_ = (u) & 3;               \
        _Pragma("unroll")                                                         \
        for (int i = 0; i < 2; ++i) {                                             \
            const int c  = i * 256 + t;                                           \
            const int r  = c >> 2, jh = c & 3;                                    \
            const int js = jh ^ ((r >> 1) & 3);                                   \
            gld_lds16(Bt2 + (size_t)tap_ * 8192 + r * 64 + c1h_ * 32 + js * 8,    \
                      Bs + slot_ * 4096 + (i * 256 + wave * 64) * 8);             \
        }                                                                         \
    }

    BSTAGE(0)
    BSTAGE(1)
    BSTAGE(2)

    f32x4 acc[2][4];
    #pragma unroll
    for (int mf = 0; mf < 2; ++mf)
        #pragma unroll
        for (int nf = 0; nf < 4; ++nf)
            #pragma unroll
            for (int r = 0; r < 4; ++r) acc[mf][nf][r] = 0.0f;

    #pragma unroll 1
    for (int u = 0; u < 18; ++u) {
        // counted wait: units u+1,u+2 may stay in flight (2 loads each, in-order)
        if (u <= 15)      asm volatile("s_waitcnt vmcnt(4)" ::: "memory");
        else if (u == 16) asm volatile("s_waitcnt vmcnt(2)" ::: "memory");
        else              asm volatile("s_waitcnt vmcnt(0)" ::: "memory");
        __builtin_amdgcn_s_barrier();
        __builtin_amdgcn_sched_barrier(0);

        if (u + 3 < 18) BSTAGE(u + 3)          // prefetch depth 3 (slot (u-1)&3: safe)

        const int tap = u >> 1, c1h = u & 1;
        const int kh = tap / 3, kw = tap % 3;
        const int par = kw & 1;
        const int rrow = 2 * wq + kh;
        const int jt = c1h * 4 + kb;
        const int slot = u & 3;

        f16x8 afr[2];
        #pragma unroll
        for (int mf = 0; mf < 2; ++mf) {
            const int ox = mf * 16 + lrow;
            const int xh = ox + (kw >> 1);
            const int p  = rrow * 64 + par * 32 + xh;
            f16x8 v = *(const f16x8*)&As[p * 64 + (jt ^ (p & 7)) * 8];
            if ((kw == 2) && (ox == 31)) v = (f16x8){};
            afr[mf] = v;
        }
        #pragma unroll
        for (int nf = 0; nf < 4; ++nf) {
            const int r = wn * 64 + nf * 16 + lrow;
            const f16x8 bfr = *(const f16x8*)&Bs[slot * 4096 + r * 32 + (kb ^ ((r >> 1) & 3)) * 8];
            #pragma unroll
            for (int mf = 0; mf < 2; ++mf)
                acc[mf][nf] = __builtin_amdgcn_mfma_f32_16x16x32_f16(afr[mf], bfr, acc[mf][nf], 0, 0, 0);
        }
    }

    float* ob = out + (size_t)bk * 128 * 1024;
    #pragma unroll
    for (int mf = 0; mf < 2; ++mf) {
        const int m0 = mc * 64 + wq * 32 + mf * 16 + kb * 4;
        #pragma unroll
        for (int nf = 0; nf < 4; ++nf) {
            const int c2 = wn * 64 + nf * 16 + lrow;
            const float bb = b2[c2];
            f32x4 v;
            #pragma unroll
            for (int r = 0; r < 4; ++r) v[r] = fmaxf(acc[mf][nf][r] + bb, 0.0f);
            *(f32x4*)(ob + (size_t)c2 * 1024 + m0) = v;
        }
    }
}

extern "C" void kernel_launch(void* const* d_in, const int* in_sizes, int n_in,
                              void* d_out, int out_size, void* d_ws, size_t ws_size,
                              hipStream_t stream) {
    const float* x  = (const float*)d_in[0];
    const float* l  = (const float*)d_in[1];
    const float* w1 = (const float*)d_in[2];
    const float* b1 = (const float*)d_in[3];
    const float* w2 = (const float*)d_in[4];
    const float* b2 = (const float*)d_in[5];
    float* out = (float*)d_out;

    _Float16* Bt1 = (_Float16*)d_ws;                                   // 2048  f16
    _Float16* Bt2 = Bt1 + 64 * 32;                                     // 73728 f16
    _Float16* h1  = (_Float16*)((char*)d_ws + 160 * 1024);             // chunked

    const int total_imgs = 192;                                        // B*K
    const size_t per_img = (size_t)4096 * 64 * sizeof(_Float16);       // 512 KB
    size_t h1_cap = (ws_size > 160 * 1024) ? ws_size - 160 * 1024 : 0;
    int ipc = (int)(h1_cap / per_img);
    if (ipc > total_imgs) ipc = total_imgs;
    if (ipc < 1) ipc = 1;

    transform_kernel<<<296, 256, 0, stream>>>(w1, w2, Bt1, Bt2);

    for (int bk0 = 0; bk0 < total_imgs; bk0 += ipc) {
        const int n = (total_imgs - bk0 < ipc) ? (total_imgs - bk0) : ipc;
        conv1_mfma<<<dim3(16, n), 256, 0, stream>>>(x, l, Bt1, b1, h1, bk0);
        conv2_mfma<<<dim3(16, n), 256, 0, stream>>>(h1, Bt2, b2, out, bk0);
    }
}

// Round 20
// 100.255 us; speedup vs baseline: 1.0626x; 1.0626x over previous
//
#include <hip/hip_runtime.h>
#include <hip/hip_bf16.h>

typedef __attribute__((ext_vector_type(4))) float  f32x4;
typedef __attribute__((ext_vector_type(8))) _Float16 f16x8;

static __device__ __forceinline__ void gld_lds16(const void* g, void* l) {
    __builtin_amdgcn_global_load_lds(
        (const __attribute__((address_space(1))) void*)g,
        (__attribute__((address_space(3))) void*)l, 16, 0, 0);
}

// ---- weight pre-transform: w1 -> Bt1[64 n][32 k] f16; w2 -> Bt2[9 tap][128 c2][64 c1] f16
__global__ void transform_kernel(const float* __restrict__ w1, const float* __restrict__ w2,
                                 _Float16* __restrict__ Bt1, _Float16* __restrict__ Bt2)
{
    const int i = blockIdx.x * 256 + threadIdx.x;
    if (i < 64 * 32) {
        const int n = i >> 5, k = i & 31;
        const float v = (k < 27) ? w1[n * 27 + k] : 0.0f;
        Bt1[i] = (_Float16)v;
    }
    const int j = i - 64 * 32;
    if (j >= 0 && j < 9 * 128 * 64) {
        const int tap = j / (128 * 64);
        const int rem = j % (128 * 64);
        const int n = rem >> 6;          // c2
        const int c1 = rem & 63;
        Bt2[j] = (_Float16)w2[((size_t)n * 64 + c1) * 9 + tap];
    }
}

// ---- conv1 (r17 measured-best): patch-LDS gather (dedup), direct fragment build
// (no im2col buffer), out_t swizzle staging + coalesced dump.
// h1: parity-split pixel p = y*64+(x&1)*32+(x>>1), c1 XOR-swizzled.
__global__ __launch_bounds__(256) void conv1_mfma(
    const float* __restrict__ x, const float* __restrict__ l,
    const _Float16* __restrict__ Bt1, const float* __restrict__ b1,
    _Float16* __restrict__ h1, int bk0)
{
    const int img = blockIdx.y;
    const int bk  = bk0 + img;
    const int b   = bk / 3, ksc = bk % 3;
    const int step = 1 << ksc;
    const int half = 32 << ksc;
    const int py0 = blockIdx.x * 4;          // first patch row of this block

    const float ly = l[b * 2 + 0], lx = l[b * 2 + 1];
    int cy = (int)floorf(0.5f * (ly + 1.0f) * 512.0f);
    int cx = (int)floorf(0.5f * (lx + 1.0f) * 512.0f);
    cy = min(max(cy, 0), 512);
    cx = min(max(cx, 0), 512);
    const int sy = cy - half, sx = cx - half;

    __shared__ float    patch[3 * 6 * 66];   // 4.75 KB unique gather window
    __shared__ _Float16 out_t[256 * 64];     // 32 KB swizzled output tile

    const int t = threadIdx.x;
    const float* xb = x + (size_t)b * 3 * 512 * 512;
    for (int i = t; i < 3 * 6 * 66; i += 256) {
        const int c  = i / 396, r = i % 396;
        const int ry = r / 66, xx = r % 66;
        const int yy = py0 - 1 + ry;
        const int col = xx - 1;
        const int iy = sy + yy * step, ix = sx + col * step;
        float v = 0.0f;
        if (yy >= 0 && yy < 64 && col >= 0 && col < 64 &&
            iy >= 0 && iy < 512 && ix >= 0 && ix < 512)
            v = xb[(size_t)c * 262144 + iy * 512 + ix];
        patch[i] = v;
    }
    __syncthreads();

    const int wave = t >> 6, lane = t & 63;
    const int lrow = lane & 15, kb = lane >> 4;

    int offj[8];
    #pragma unroll
    for (int j = 0; j < 8; ++j) {
        const int k  = kb * 8 + j;
        const int c  = (k * 57) >> 9;        // k/9 (k < 512)
        const int rr = k - c * 9;
        const int kh = (rr * 43) >> 7;       // rr/3 (rr < 9)
        const int kw = rr - kh * 3;
        offj[j] = (k < 27) ? (c * 396 + kh * 66 + kw) : -1;
    }

    f16x8 bfr[4];
    #pragma unroll
    for (int nf = 0; nf < 4; ++nf)
        bfr[nf] = *(const f16x8*)(Bt1 + ((size_t)(nf * 16 + lrow)) * 32 + kb * 8);

    f32x4 acc[4][4];
    #pragma unroll
    for (int mf = 0; mf < 4; ++mf)
        #pragma unroll
        for (int nf = 0; nf < 4; ++nf)
            #pragma unroll
            for (int r = 0; r < 4; ++r) acc[mf][nf][r] = 0.0f;

    #pragma unroll
    for (int mf = 0; mf < 4; ++mf) {
        const int pix   = (wave * 4 + mf) * 16 + lrow;
        const int pbase = (pix >> 6) * 66 + (pix & 63);
        f16x8 afr;
        #pragma unroll
        for (int j = 0; j < 8; ++j)
            afr[j] = (offj[j] >= 0) ? (_Float16)patch[offj[j] + pbase] : (_Float16)0.0f;
        #pragma unroll
        for (int nf = 0; nf < 4; ++nf)
            acc[mf][nf] = __builtin_amdgcn_mfma_f32_16x16x32_f16(afr, bfr[nf], acc[mf][nf], 0, 0, 0);
    }

    #pragma unroll
    for (int mf = 0; mf < 4; ++mf) {
        const int ml0 = (wave * 4 + mf) * 16 + kb * 4;
        #pragma unroll
        for (int nf = 0; nf < 4; ++nf) {
            const int c1 = nf * 16 + lrow;
            const float bb = b1[c1];
            #pragma unroll
            for (int r = 0; r < 4; ++r) {
                const float v = fmaxf(acc[mf][nf][r] + bb, 0.0f);
                const int ml = ml0 + r;
                const int xcol = ml & 63;
                const int psx = ((xcol & 1) << 5) | (xcol >> 1);   // parity split
                const int pl  = (ml & ~63) | psx;
                const int c1s = c1 ^ ((psx & 7) << 3);             // bank swizzle
                out_t[pl * 64 + c1s] = (_Float16)v;
            }
        }
    }
    __syncthreads();

    _Float16* hb = h1 + (size_t)img * 4096 * 64 + (size_t)py0 * 64 * 64;
    #pragma unroll
    for (int j = 0; j < 8; ++j) {
        const int idx = j * 256 + t;
        *(f16x8*)(hb + (size_t)idx * 8) = *(const f16x8*)&out_t[idx * 8];
    }
}

// ---- conv2 (r8 structure, measured-best): LDS-staged implicit GEMM.
// Block = (img, mc: 2 out rows) x N=128. 2x2 wave split: wave tile M=32 x N=64.
// LDS: A slab 5 h1-rows (40KB) + B double-buffer 2x16KB = 72KB -> 2 blocks/CU.
__global__ __launch_bounds__(256) void conv2_mfma(
    const _Float16* __restrict__ h1, const _Float16* __restrict__ Bt2,
    const float* __restrict__ b2, float* __restrict__ out, int bk0)
{
    const int img = blockIdx.y;
    const int bk  = bk0 + img;
    const int mc  = blockIdx.x;               // 0..15 : 2 out rows (64 px)
    const int t = threadIdx.x, wave = t >> 6, lane = t & 63;
    const int lrow = lane & 15, kb = lane >> 4;
    const int wq = wave >> 1;                 // M half (0..1)
    const int wn = wave & 1;                  // N half (0..1)

    __shared__ _Float16 As[5 * 4096 + 2 * 8192];   // 40KB A + 32KB B = 72KB
    _Float16* Bs = As + 5 * 4096;

    const _Float16* hb = h1 + (size_t)img * 4096 * 64;
    const int ys = mc * 4;
    const int nrows = (mc == 15) ? 4 : 5;

    if (mc == 15) {                            // zero pad_high row (y=64)
        f16x8 z = {};
        *(f16x8*)&As[4 * 4096 + t * 16]     = z;
        *(f16x8*)&As[4 * 4096 + t * 16 + 8] = z;
    }

    {   // stage A slab
        const _Float16* ga = hb + (size_t)ys * 4096;
        #pragma unroll
        for (int j = 0; j < 10; ++j) {
            if (j < nrows * 2) {
                const int c = j * 256 + t;
                gld_lds16(ga + (size_t)c * 8, As + (j * 256 + wave * 64) * 8);
            }
        }
    }
    {   // stage B tap 0 into slot 0 (pre-swizzled source)
        #pragma unroll
        for (int i = 0; i < 4; ++i) {
            const int c = i * 256 + t;
            const int r = c >> 3, j = c & 7;
            const int jt = j ^ (r & 7);
            gld_lds16(Bt2 + (size_t)r * 64 + jt * 8,
                      Bs + (i * 256 + wave * 64) * 8);
        }
    }

    f32x4 acc[2][4];
    #pragma unroll
    for (int mf = 0; mf < 2; ++mf)
        #pragma unroll
        for (int nf = 0; nf < 4; ++nf)
            #pragma unroll
            for (int r = 0; r < 4; ++r) acc[mf][nf][r] = 0.0f;

    #pragma unroll 1
    for (int tap = 0; tap < 9; ++tap) {
        __syncthreads();                      // stage(tap) ready (drains vmcnt)
        if (tap < 8) {                        // stage B tap+1 into other slot
            const _Float16* gb = Bt2 + (size_t)(tap + 1) * 8192;
            const int slot = (tap + 1) & 1;
            #pragma unroll
            for (int i = 0; i < 4; ++i) {
                const int c = i * 256 + t;
                const int r = c >> 3, j = c & 7;
                const int jt = j ^ (r & 7);
                gld_lds16(gb + (size_t)r * 64 + jt * 8,
                          Bs + slot * 8192 + (i * 256 + wave * 64) * 8);
            }
        }
        const int kh = tap / 3, kw = tap % 3;
        const int par = kw & 1;
        const int rrow = 2 * wq + kh;
        const int slot = tap & 1;

        #pragma unroll
        for (int c1h = 0; c1h < 2; ++c1h) {
            const int jt = c1h * 4 + kb;
            f16x8 afr[2];
            #pragma unroll
            for (int mf = 0; mf < 2; ++mf) {
                const int ox = mf * 16 + lrow;
                const int xh = ox + (kw >> 1);
                const int p  = rrow * 64 + par * 32 + xh;
                f16x8 v = *(const f16x8*)&As[p * 64 + (jt ^ (p & 7)) * 8];
                if ((kw == 2) && (ox == 31)) v = (f16x8){};
                afr[mf] = v;
            }
            #pragma unroll
            for (int nf = 0; nf < 4; ++nf) {
                const int r = wn * 64 + nf * 16 + lrow;
                const f16x8 bfr = *(const f16x8*)&Bs[slot * 8192 + r * 64 + (jt ^ (r & 7)) * 8];
                #pragma unroll
                for (int mf = 0; mf < 2; ++mf)
                    acc[mf][nf] = __builtin_amdgcn_mfma_f32_16x16x32_f16(afr[mf], bfr, acc[mf][nf], 0, 0, 0);
            }
        }
    }

    float* ob = out + (size_t)bk * 128 * 1024;
    #pragma unroll
    for (int mf = 0; mf < 2; ++mf) {
        const int m0 = mc * 64 + wq * 32 + mf * 16 + kb * 4;
        #pragma unroll
        for (int nf = 0; nf < 4; ++nf) {
            const int c2 = wn * 64 + nf * 16 + lrow;
            const float bb = b2[c2];
            f32x4 v;
            #pragma unroll
            for (int r = 0; r < 4; ++r) v[r] = fmaxf(acc[mf][nf][r] + bb, 0.0f);
            *(f32x4*)(ob + (size_t)c2 * 1024 + m0) = v;
        }
    }
}

extern "C" void kernel_launch(void* const* d_in, const int* in_sizes, int n_in,
                              void* d_out, int out_size, void* d_ws, size_t ws_size,
                              hipStream_t stream) {
    const float* x  = (const float*)d_in[0];
    const float* l  = (const float*)d_in[1];
    const float* w1 = (const float*)d_in[2];
    const float* b1 = (const float*)d_in[3];
    const float* w2 = (const float*)d_in[4];
    const float* b2 = (const float*)d_in[5];
    float* out = (float*)d_out;

    _Float16* Bt1 = (_Float16*)d_ws;                                   // 2048  f16
    _Float16* Bt2 = Bt1 + 64 * 32;                                     // 73728 f16
    _Float16* h1  = (_Float16*)((char*)d_ws + 160 * 1024);             // chunked

    const int total_imgs = 192;                                        // B*K
    const size_t per_img = (size_t)4096 * 64 * sizeof(_Float16);       // 512 KB
    size_t h1_cap = (ws_size > 160 * 1024) ? ws_size - 160 * 1024 : 0;
    int ipc = (int)(h1_cap / per_img);
    if (ipc > total_imgs) ipc = total_imgs;
    if (ipc < 1) ipc = 1;

    transform_kernel<<<296, 256, 0, stream>>>(w1, w2, Bt1, Bt2);

    for (int bk0 = 0; bk0 < total_imgs; bk0 += ipc) {
        const int n = (total_imgs - bk0 < ipc) ? (total_imgs - bk0) : ipc;
        conv1_mfma<<<dim3(16, n), 256, 0, stream>>>(x, l, Bt1, b1, h1, bk0);
        conv2_mfma<<<dim3(16, n), 256, 0, stream>>>(h1, Bt2, b2, out, bk0);
    }
}